// Round 3
// baseline (166.246 us; speedup 1.0000x reference)
//
#include <hip/hip_runtime.h>
#include <hip/hip_bf16.h>

typedef unsigned short u16;
typedef __attribute__((ext_vector_type(8))) short short8;
typedef __attribute__((ext_vector_type(4))) float floatx4;

#define NB 32
#define NCI 256
#define NCO 256
#define NW 4096
#define NK 5

#define XTROWS 4100
#define W3ROWB 80               // 32 bf16 + 16B pad per co-row
#define W3TILE (256 * W3ROWB)   // 20480 B per (cb,tap) tile
#define W3_BYTES (40 * W3TILE)  // 819200
#define XT_BYTES ((size_t)NB * 8 * XTROWS * 32 * 2)  // 67174400

// ---------------- pre-kernels ----------------

__global__ void wprep(const float* __restrict__ wgt, u16* __restrict__ W3) {
    int i = blockIdx.x * 256 + threadIdx.x;       // co*1280 + ci*5 + k
    if (i >= NCO * NCI * NK) return;
    int k  = i % NK;
    int ci = (i / NK) % NCI;
    int co = i / (NCI * NK);
    int cb = ci >> 5, cr = ci & 31;
    __hip_bfloat16 h = __float2bfloat16(wgt[i]);
    W3[((size_t)(cb * NK + k) * 256 + co) * 40 + cr] = *reinterpret_cast<u16*>(&h);
}

__global__ void xprep(const float* __restrict__ x, u16* __restrict__ xT) {
    // grid (128 w-tiles, 8 ci-blocks, 32 b); block 256 = 32x8; fused halo-zero
    int wt = blockIdx.x, cb = blockIdx.y, b = blockIdx.z;
    int tx = threadIdx.x & 31, ty = threadIdx.x >> 5;
    __shared__ float sh[32][33];
    int w0 = wt * 32, c0 = cb * 32;
    const float* xb = x + ((size_t)b * NCI + c0) * NW + w0;
#pragma unroll
    for (int r = 0; r < 4; r++)
        sh[ty + 8 * r][tx] = xb[(size_t)(ty + 8 * r) * NW + tx];
    // halo rows (w = -2,-1 and 4096,4097 -> xT rows 0,1,4098,4099) zeroed
    if (wt == 0 && threadIdx.x < 64)
        xT[((size_t)(b * 8 + cb) * XTROWS + (threadIdx.x >> 5)) * 32 + (threadIdx.x & 31)] = 0;
    if (wt == 127 && threadIdx.x < 64)
        xT[((size_t)(b * 8 + cb) * XTROWS + 4098 + (threadIdx.x >> 5)) * 32 + (threadIdx.x & 31)] = 0;
    __syncthreads();
    u16* dst = xT + ((size_t)(b * 8 + cb) * XTROWS + w0 + 2) * 32;
#pragma unroll
    for (int r = 0; r < 4; r++) {
        __hip_bfloat16 h = __float2bfloat16(sh[tx][ty + 8 * r]);
        dst[(size_t)(ty + 8 * r) * 32 + tx] = *reinterpret_cast<u16*>(&h);
    }
}

// ---------------- main MFMA conv ----------------
// block = 256co x 256w, 8 waves (wm in {0,1}, wn in {0..3}), wave tile 128x64.
// W: LDS double-buffer, T14 reg-staged (NO global_load_lds -> no DMA race).
// X: straight from global xT (L1-resident slab per (b,cb)).

__global__ __launch_bounds__(512, 2)
void conv_mfma(const u16* __restrict__ W3, const u16* __restrict__ xT,
               const float* __restrict__ bias, float* __restrict__ out) {
    __shared__ __align__(16) char smem[2 * W3TILE];   // 40 KB

    int bid  = blockIdx.x;
    int wt   = bid & 15;           // 16 w-tiles of 256
    int b    = bid >> 4;           // batch
    int tid  = threadIdx.x;
    int lane = tid & 63, wave = tid >> 6;
    int wm   = wave >> 2, wn = wave & 3;
    int mrow = lane & 15, g = lane >> 4;
    int w0   = wt * 256;

    floatx4 acc[8][4];
#pragma unroll
    for (int mi = 0; mi < 8; mi++)
#pragma unroll
        for (int ni = 0; ni < 4; ni++)
            acc[mi][ni] = (floatx4){0.f, 0.f, 0.f, 0.f};

    const char* w3 = (const char*)W3;

    // prologue: reg-stage tile 0 (20480 B = 512thr*16B + 512thr*16B + 256thr*16B)
    {
        int4 a0 = *(const int4*)(w3 + tid * 16);
        int4 a1 = *(const int4*)(w3 + (tid + 512) * 16);
        int4 a2 = {};
        if (tid < 256) a2 = *(const int4*)(w3 + (tid + 1024) * 16);
        *(int4*)(smem + tid * 16) = a0;
        *(int4*)(smem + (tid + 512) * 16) = a1;
        if (tid < 256) *(int4*)(smem + (tid + 1024) * 16) = a2;
    }
    __syncthreads();

    int buf = 0;
    for (int cb = 0; cb < 8; ++cb) {
        const char* xbase = (const char*)xT +
            ((size_t)((b * 8 + cb) * XTROWS + w0 + wn * 64 + mrow)) * 64 + g * 16;
#pragma unroll
        for (int t = 0; t < NK; ++t) {
            int s = cb * NK + t;
            char* cur = smem + buf * W3TILE;
            char* nxt = smem + (buf ^ 1) * W3TILE;

            // T14 issue-early: global loads for tile s+1 into registers
            int4 sA = {}, sB = {}, sC = {};
            bool st = (s < 39);
            if (st) {
                const char* src = w3 + (size_t)(s + 1) * W3TILE;
                sA = *(const int4*)(src + tid * 16);
                sB = *(const int4*)(src + (tid + 512) * 16);
                if (tid < 256) sC = *(const int4*)(src + (tid + 1024) * 16);
            }

            short8 af[8], bf[4];
#pragma unroll
            for (int mi = 0; mi < 8; mi++)
                af[mi] = *(const short8*)(cur +
                         (wm * 128 + mi * 16 + mrow) * W3ROWB + g * 16);
#pragma unroll
            for (int ni = 0; ni < 4; ni++)
                bf[ni] = *(const short8*)(xbase + (size_t)(ni * 16 + t) * 64);

            __builtin_amdgcn_s_setprio(1);
#pragma unroll
            for (int mi = 0; mi < 8; mi++)
#pragma unroll
                for (int ni = 0; ni < 4; ni++)
                    acc[mi][ni] = __builtin_amdgcn_mfma_f32_16x16x32_bf16(
                        af[mi], bf[ni], acc[mi][ni], 0, 0, 0);
            __builtin_amdgcn_s_setprio(0);

            // T14 write-late: ds_write staged regs (HBM latency hid under MFMA)
            if (st) {
                *(int4*)(nxt + tid * 16) = sA;
                *(int4*)(nxt + (tid + 512) * 16) = sB;
                if (tid < 256) *(int4*)(nxt + (tid + 1024) * 16) = sC;
            }
            __syncthreads();   // lgkmcnt drain orders ds_write -> next ds_read
            buf ^= 1;
        }
    }

    // epilogue: C/D layout col=lane&15, row=g*4+reg (m89-verified)
#pragma unroll
    for (int mi = 0; mi < 8; mi++) {
        int cobase = wm * 128 + mi * 16 + g * 4;
        float bv[4];
#pragma unroll
        for (int r = 0; r < 4; r++) bv[r] = bias[cobase + r];
#pragma unroll
        for (int ni = 0; ni < 4; ni++) {
            int col = w0 + wn * 64 + ni * 16 + mrow;
#pragma unroll
            for (int r = 0; r < 4; r++)
                out[((size_t)b * NCO + cobase + r) * NW + col] =
                    acc[mi][ni][r] + bv[r];
        }
    }
}

// ---------------- fallback (ws too small): naive fp32 ----------------

__global__ void conv_naive(const float* __restrict__ x, const float* __restrict__ wgt,
                           const float* __restrict__ bias, float* __restrict__ out) {
    int w  = blockIdx.x * 256 + threadIdx.x;
    int co = blockIdx.y;
    int b  = blockIdx.z;
    float acc = bias[co];
    for (int ci = 0; ci < NCI; ci++) {
        const float* xr = x + ((size_t)b * NCI + ci) * NW;
        const float* wr = wgt + ((size_t)co * NCI + ci) * NK;
#pragma unroll
        for (int k = 0; k < NK; k++) {
            int wi = w + k - 2;
            if (wi >= 0 && wi < NW) acc += xr[wi] * wr[k];
        }
    }
    out[((size_t)b * NCO + co) * NW + w] = acc;
}

// ---------------- launch ----------------

extern "C" void kernel_launch(void* const* d_in, const int* in_sizes, int n_in,
                              void* d_out, int out_size, void* d_ws, size_t ws_size,
                              hipStream_t stream) {
    const float* x    = (const float*)d_in[0];
    const float* wgt  = (const float*)d_in[1];
    const float* bias = (const float*)d_in[2];
    float* out        = (float*)d_out;

    size_t need = (size_t)W3_BYTES + XT_BYTES;
    if (ws_size < need) {
        conv_naive<<<dim3(NW / 256, NCO, NB), 256, 0, stream>>>(x, wgt, bias, out);
        return;
    }

    u16* W3 = (u16*)d_ws;
    u16* xT = (u16*)((char*)d_ws + W3_BYTES);

    wprep<<<(NCO * NCI * NK + 255) / 256, 256, 0, stream>>>(wgt, W3);
    xprep<<<dim3(NW / 32, 8, NB), 256, 0, stream>>>(x, xT);
    conv_mfma<<<512, 512, 0, stream>>>(W3, xT, bias, out);
}